// Round 16
// baseline (36.017 us; speedup 1.0000x reference)
//
#include <hip/hip_runtime.h>
#include <hip/hip_bf16.h>

// Problem constants (fixed by setup_inputs)
#define NB 8
#define G  2048
#define C  512
#define CH 8
#define NM 4
#define HD 10
#define NS 10
#define L1 1022
#define L2 509
#define L3 253
#define L4 125

// ---------------- Kernel 1: RBF density + datarepr (R13-exact inner loop) -------
// 2048 blocks x 256 threads (8 blocks/CU, 32 waves/CU). Block = (b,H, 64 g's);
// wave wv sums c-chunk [wv*128, wv*128+128). xc/yc slice staged once as float2
// in LDS; inner loop = ds_read_b64 (uniform addr -> broadcast) + 5 VALU + v_exp.
__global__ __launch_bounds__(256) void k_density(
    const float* __restrict__ xc, const float* __restrict__ yc,
    const float* __restrict__ xg, const float* __restrict__ logls,
    float* __restrict__ out_den,   // (nb,G,ch)
    float* __restrict__ out_rep,   // (nb,G,ch)
    int* __restrict__ cnt)         // 8 ticket counters for k_convnet tail blocks
{
    __shared__ float2 sxy[C];        // 4 KB: (xx, yy) for this (b,H)
    __shared__ float sden[4][64];
    __shared__ float snum[4][64];
    const int tid  = threadIdx.x;
    const int lane = tid & 63;
    const int wv   = tid >> 6;
    const int id = blockIdx.x;                 // 0..2047 = ((b*8+H)*32+gt)
    const int gt = id & 31;
    const int H  = (id >> 5) & 7;
    const int b  = id >> 8;

    if (id == 0 && tid < NB) cnt[tid] = 0;     // re-zero tickets every call

    for (int c = tid; c < C; c += 256)
        sxy[c] = make_float2(xc[(b * C + c) * CH + H], yc[(b * C + c) * CH + H]);
    __syncthreads();

    const int g = gt * 64 + lane;
    const float x = xg[(b * G + g) * CH + H];
    // exp(-0.5 d^2/ls^2) == exp2( (-0.5*log2e/ls^2) * d^2 )
    const float coef = -0.72134752044448170f * __expf(-2.0f * logls[H]);

    const float2* p = sxy + wv * 128;
    float den = 0.0f, num = 0.0f;
    #pragma unroll 8
    for (int c = 0; c < 128; ++c) {
        const float2 v = p[c];                 // ds_read_b64, broadcast
        const float d = x - v.x;
        const float w = __builtin_amdgcn_exp2f((d * coef) * d);
        den += w;
        num = fmaf(w, v.y, num);
    }

    sden[wv][lane] = den;
    snum[wv][lane] = num;
    __syncthreads();

    if (tid < 64) {
        const float dtot = sden[0][tid] + sden[1][tid] + sden[2][tid] + sden[3][tid];
        const float ntot = snum[0][tid] + snum[1][tid] + snum[2][tid] + snum[3][tid];
        const int o = (b * G + gt * 64 + tid) * CH + H;
        out_den[o] = dtot;
        out_rep[o] = ntot / (dtot + 1e-4f);
    }
}

// ---------------- Kernel 2: conv chain (blocks 0..199) + tail (blocks 200..207) --
// Conv tile t of batch b covers l4 in [5t,5t+5) (halo recompute, all LDS).
// Conv blocks ticket cnt[b] when their h4 tile is globally visible; the 8 tail
// blocks spin until cnt[b]==25, then run pool+linear+softmax+gumbel.
__global__ __launch_bounds__(256) void k_convnet(
    const float* __restrict__ rep,
    const float* __restrict__ w1, const float* __restrict__ b1,
    const float* __restrict__ w2, const float* __restrict__ b2,
    const float* __restrict__ w3, const float* __restrict__ b3,
    const float* __restrict__ w4, const float* __restrict__ b4,
    const float* __restrict__ wl, const float* __restrict__ bl,
    const float* __restrict__ unif,
    float* __restrict__ h4out,    // (NB, HD, L4) in ws
    int* __restrict__ cnt,
    float* __restrict__ out_mw,   // (NB, CH, NM)
    float* __restrict__ out_ms)   // (NB, NS, CH, NM)
{
    const int tid = threadIdx.x;

    if (blockIdx.x >= NB * 25) {
        // ---------------- tail block for b ----------------
        const int b = blockIdx.x - NB * 25;
        __shared__ float red[HD * 25];
        __shared__ float hm[HD];
        __shared__ float lg[CH * NM];
        __shared__ float ltt[CH * NM];

        if (tid == 0) {
            while (__hip_atomic_load(&cnt[b], __ATOMIC_RELAXED,
                                     __HIP_MEMORY_SCOPE_AGENT) < 25)
                __builtin_amdgcn_s_sleep(16);
        }
        __syncthreads();
        __threadfence();   // acquire: h4 writes of all 25 conv blocks

        if (tid < HD * 25) {
            const int o = tid / 25, j = tid % 25;
            const float* p = h4out + (b * HD + o) * L4 + j * 5;
            red[tid] = p[0] + p[1] + p[2] + p[3] + p[4];
        }
        __syncthreads();
        if (tid < HD) {
            float s = 0.0f;
            #pragma unroll
            for (int j = 0; j < 25; ++j) s += red[tid * 25 + j];
            hm[tid] = s * (1.0f / (float)L4);
        }
        __syncthreads();
        if (tid < CH * NM) {
            float acc = bl[tid];
            #pragma unroll
            for (int k = 0; k < HD; ++k) acc = fmaf(wl[tid * HD + k], hm[k], acc);
            lg[tid] = acc;
        }
        __syncthreads();
        if (tid < CH) {
            float lv[NM];
            #pragma unroll
            for (int m = 0; m < NM; ++m) lv[m] = lg[tid * NM + m];
            const float m0 = fmaxf(fmaxf(lv[0], lv[1]), fmaxf(lv[2], lv[3]));
            float e[NM], s = 0.0f;
            #pragma unroll
            for (int m = 0; m < NM; ++m) {
                const float v = (lv[m] - m0) / 0.1f;
                ltt[tid * NM + m] = v;
                e[m] = __expf(v);
                s += e[m];
            }
            #pragma unroll
            for (int m = 0; m < NM; ++m)
                out_mw[(b * CH + tid) * NM + m] = e[m] / s;
        }
        __syncthreads();
        if (tid < NS * CH) {
            const int c = tid % CH, sI = tid / CH;
            const float* up = unif + ((b * NS + sI) * CH + c) * NM;
            float hh[NM], mx = -1e30f;
            #pragma unroll
            for (int m = 0; m < NM; ++m) {
                const float gu = -__logf(-__logf(up[m] + 1e-8f));
                hh[m] = (gu + ltt[c * NM + m]) / 0.1f;
                mx = fmaxf(mx, hh[m]);
            }
            float e2[NM], ss = 0.0f;
            #pragma unroll
            for (int m = 0; m < NM; ++m) { e2[m] = __expf(hh[m] - mx); ss += e2[m]; }
            #pragma unroll
            for (int m = 0; m < NM; ++m) {
                float y = e2[m] / ss;
                y = fminf(fmaxf(y, 1e-8f), 1.0f - 1e-8f);
                out_ms[((b * NS + sI) * CH + c) * NM + m] = y;
            }
        }
        return;
    }

    // ---------------- conv tile block ----------------
    const int b = blockIdx.x / 25;
    const int t = blockIdx.x % 25;

    __shared__ float sxt[CH * 125];      // rep tile, [ci][125]
    __shared__ float sw1[5 * CH * HD];   // [k][ci][o]
    __shared__ float sw2[5 * HD * HD];
    __shared__ float sw3[5 * HD * HD];
    __shared__ float sw4[5 * HD * HD];
    __shared__ float s1[HD * 61];        // [ci][61]
    __shared__ float s2[HD * 29];
    __shared__ float s3[HD * 13];

    {
        const float* src = rep + (b * G + 80 * t) * CH;
        for (int i = tid; i < 125 * CH; i += 256) {
            const int gl = i >> 3, ci = i & 7;
            sxt[ci * 125 + gl] = src[i];
        }
    }
    for (int i = tid; i < HD * CH * 5; i += 256) {
        const int o = i / 40, ci = (i / 5) % 8, k = i % 5;
        sw1[(k * CH + ci) * HD + o] = w1[i];
    }
    for (int i = tid; i < HD * HD * 5; i += 256) {
        const int o = i / 50, ci = (i / 5) % 10, k = i % 5;
        sw2[(k * HD + ci) * HD + o] = w2[i];
        sw3[(k * HD + ci) * HD + o] = w3[i];
        sw4[(k * HD + ci) * HD + o] = w4[i];
    }
    __syncthreads();

    for (int i = tid; i < 61 * HD; i += 256) {
        const int o = i % HD, ll = i / HD;
        float acc = b1[o];
        #pragma unroll
        for (int k = 0; k < 5; ++k)
            #pragma unroll
            for (int ci = 0; ci < CH; ++ci)
                acc = fmaf(sxt[ci * 125 + 2 * ll + k], sw1[(k * CH + ci) * HD + o], acc);
        s1[o * 61 + ll] = fmaxf(acc, 0.0f);
    }
    __syncthreads();

    for (int i = tid; i < 29 * HD; i += 256) {
        const int o = i % HD, ll = i / HD;
        float acc = b2[o];
        #pragma unroll
        for (int k = 0; k < 5; ++k)
            #pragma unroll
            for (int ci = 0; ci < HD; ++ci)
                acc = fmaf(s1[ci * 61 + 2 * ll + k], sw2[(k * HD + ci) * HD + o], acc);
        s2[o * 29 + ll] = fmaxf(acc, 0.0f);
    }
    __syncthreads();

    for (int i = tid; i < 13 * HD; i += 256) {
        const int o = i % HD, ll = i / HD;
        float acc = b3[o];
        #pragma unroll
        for (int k = 0; k < 5; ++k)
            #pragma unroll
            for (int ci = 0; ci < HD; ++ci)
                acc = fmaf(s2[ci * 29 + 2 * ll + k], sw3[(k * HD + ci) * HD + o], acc);
        s3[o * 13 + ll] = fmaxf(acc, 0.0f);
    }
    __syncthreads();

    for (int i = tid; i < 5 * HD; i += 256) {
        const int o = i % HD, ll = i / HD;
        float acc = b4[o];
        #pragma unroll
        for (int k = 0; k < 5; ++k)
            #pragma unroll
            for (int ci = 0; ci < HD; ++ci)
                acc = fmaf(s3[ci * 13 + 2 * ll + k], sw4[(k * HD + ci) * HD + o], acc);
        h4out[(b * HD + o) * L4 + 5 * t + ll] = acc;
    }

    __syncthreads();
    if (tid == 0) {
        __threadfence();                       // release h4 tile
        atomicAdd(&cnt[b], 1);
    }
}

extern "C" void kernel_launch(void* const* d_in, const int* in_sizes, int n_in,
                              void* d_out, int out_size, void* d_ws, size_t ws_size,
                              hipStream_t stream) {
    const float* xc    = (const float*)d_in[0];
    const float* yc    = (const float*)d_in[1];
    const float* xg    = (const float*)d_in[2];
    const float* logls = (const float*)d_in[3];
    const float* w1    = (const float*)d_in[4];
    const float* b1    = (const float*)d_in[5];
    const float* w2    = (const float*)d_in[6];
    const float* b2    = (const float*)d_in[7];
    const float* w3    = (const float*)d_in[8];
    const float* b3    = (const float*)d_in[9];
    const float* w4    = (const float*)d_in[10];
    const float* b4    = (const float*)d_in[11];
    const float* wl    = (const float*)d_in[12];
    const float* bl    = (const float*)d_in[13];
    const float* unif  = (const float*)d_in[14];

    float* out = (float*)d_out;                 // reference outputs are float32
    float* out_den = out;                       // 131072
    float* out_rep = out + NB * G * CH;         // 131072
    float* out_mw  = out + 2 * NB * G * CH;     // 256
    float* out_ms  = out_mw + NB * CH * NM;     // 2560
    (void)out_size; (void)in_sizes; (void)n_in; (void)ws_size;

    float* ws_h4 = (float*)d_ws;                // NB*HD*L4 = 10000 f32
    int*   cnt   = (int*)(ws_h4 + NB * HD * L4);// 8 ints

    k_density<<<2048, 256, 0, stream>>>(xc, yc, xg, logls, out_den, out_rep, cnt);

    k_convnet<<<NB * 25 + NB, 256, 0, stream>>>(out_rep, w1, b1, w2, b2, w3, b3,
                                                w4, b4, wl, bl, unif,
                                                ws_h4, cnt, out_mw, out_ms);
}

// Round 17
// 27.769 us; speedup vs baseline: 1.2970x; 1.2970x over previous
//
#include <hip/hip_runtime.h>
#include <hip/hip_bf16.h>

// Problem constants (fixed by setup_inputs)
#define NB 8
#define G  2048
#define C  512
#define CH 8
#define NM 4
#define HD 10
#define NS 10
#define L1 1022
#define L2 509
#define L3 253
#define L4 125

// ---------------- Kernel 1: RBF density + datarepr (sqrt-folded inner loop) -----
// 2048 blocks x 256 threads (8 blocks/CU, 32 waves/CU). Block = (b,H, 64 g's);
// wave wv sums c-chunk [wv*128, wv*128+128). LDS float2 = (s*xx, yy), s=sqrt(-coef).
// arg = coef(x-xx)^2 = -(s*x - s*xx)^2 -> inner loop: ds_read_b64 (broadcast) +
// sub + mul(neg-mod) + v_exp + add + fma  (4 VALU + 1 trans + 1 LDS per c).
__global__ __launch_bounds__(256) void k_density(
    const float* __restrict__ xc, const float* __restrict__ yc,
    const float* __restrict__ xg, const float* __restrict__ logls,
    float* __restrict__ out_den,   // (nb,G,ch)
    float* __restrict__ out_rep)   // (nb,G,ch)
{
    __shared__ float2 sxy[C];        // 4 KB: (s*xx, yy) for this (b,H)
    __shared__ float sden[4][64];
    __shared__ float snum[4][64];
    const int tid  = threadIdx.x;
    const int lane = tid & 63;
    const int wv   = tid >> 6;
    const int id = blockIdx.x;                 // 0..2047 = ((b*8+H)*32+gt)
    const int gt = id & 31;
    const int H  = (id >> 5) & 7;
    const int b  = id >> 8;

    // exp(-0.5 d^2/ls^2) == exp2( coef * d^2 ), coef = -0.5*log2(e)/ls^2 < 0
    const float coef = -0.72134752044448170f * __expf(-2.0f * logls[H]);
    const float s    = __builtin_amdgcn_sqrtf(-coef);

    for (int c = tid; c < C; c += 256)
        sxy[c] = make_float2(s * xc[(b * C + c) * CH + H], yc[(b * C + c) * CH + H]);
    __syncthreads();

    const int g = gt * 64 + lane;
    const float sx = s * xg[(b * G + g) * CH + H];

    const float2* p = sxy + wv * 128;
    float den = 0.0f, num = 0.0f;
    #pragma unroll 8
    for (int c = 0; c < 128; ++c) {
        const float2 v = p[c];                 // ds_read_b64, broadcast
        const float d = sx - v.x;
        const float w = __builtin_amdgcn_exp2f(-(d * d));   // v_mul neg-mod + v_exp
        den += w;
        num = fmaf(w, v.y, num);
    }

    sden[wv][lane] = den;
    snum[wv][lane] = num;
    __syncthreads();

    if (tid < 64) {
        const float dtot = sden[0][tid] + sden[1][tid] + sden[2][tid] + sden[3][tid];
        const float ntot = snum[0][tid] + snum[1][tid] + snum[2][tid] + snum[3][tid];
        const int o = (b * G + gt * 64 + tid) * CH + H;
        out_den[o] = dtot;
        out_rep[o] = ntot / (dtot + 1e-4f);
    }
}

// ---------------- Kernel 2: full conv1..4 stencil chain, tiled with halo -------
__global__ __launch_bounds__(256) void k_convnet(
    const float* __restrict__ rep,
    const float* __restrict__ w1, const float* __restrict__ b1,
    const float* __restrict__ w2, const float* __restrict__ b2,
    const float* __restrict__ w3, const float* __restrict__ b3,
    const float* __restrict__ w4, const float* __restrict__ b4,
    float* __restrict__ h4out)   // (NB, HD, L4)
{
    const int b   = blockIdx.x / 25;
    const int t   = blockIdx.x % 25;
    const int tid = threadIdx.x;

    __shared__ float sxt[CH * 125];      // rep tile, [ci][125]
    __shared__ float sw1[5 * CH * HD];   // [k][ci][o]
    __shared__ float sw2[5 * HD * HD];
    __shared__ float sw3[5 * HD * HD];
    __shared__ float sw4[5 * HD * HD];
    __shared__ float s1[HD * 61];        // [ci][61]
    __shared__ float s2[HD * 29];
    __shared__ float s3[HD * 13];

    {
        const float* src = rep + (b * G + 80 * t) * CH;
        for (int i = tid; i < 125 * CH; i += 256) {
            const int gl = i >> 3, ci = i & 7;
            sxt[ci * 125 + gl] = src[i];
        }
    }
    for (int i = tid; i < HD * CH * 5; i += 256) {
        const int o = i / 40, ci = (i / 5) % 8, k = i % 5;
        sw1[(k * CH + ci) * HD + o] = w1[i];
    }
    for (int i = tid; i < HD * HD * 5; i += 256) {
        const int o = i / 50, ci = (i / 5) % 10, k = i % 5;
        sw2[(k * HD + ci) * HD + o] = w2[i];
        sw3[(k * HD + ci) * HD + o] = w3[i];
        sw4[(k * HD + ci) * HD + o] = w4[i];
    }
    __syncthreads();

    for (int i = tid; i < 61 * HD; i += 256) {
        const int o = i % HD, ll = i / HD;
        float acc = b1[o];
        #pragma unroll
        for (int k = 0; k < 5; ++k)
            #pragma unroll
            for (int ci = 0; ci < CH; ++ci)
                acc = fmaf(sxt[ci * 125 + 2 * ll + k], sw1[(k * CH + ci) * HD + o], acc);
        s1[o * 61 + ll] = fmaxf(acc, 0.0f);
    }
    __syncthreads();

    for (int i = tid; i < 29 * HD; i += 256) {
        const int o = i % HD, ll = i / HD;
        float acc = b2[o];
        #pragma unroll
        for (int k = 0; k < 5; ++k)
            #pragma unroll
            for (int ci = 0; ci < HD; ++ci)
                acc = fmaf(s1[ci * 61 + 2 * ll + k], sw2[(k * HD + ci) * HD + o], acc);
        s2[o * 29 + ll] = fmaxf(acc, 0.0f);
    }
    __syncthreads();

    for (int i = tid; i < 13 * HD; i += 256) {
        const int o = i % HD, ll = i / HD;
        float acc = b3[o];
        #pragma unroll
        for (int k = 0; k < 5; ++k)
            #pragma unroll
            for (int ci = 0; ci < HD; ++ci)
                acc = fmaf(s2[ci * 29 + 2 * ll + k], sw3[(k * HD + ci) * HD + o], acc);
        s3[o * 13 + ll] = fmaxf(acc, 0.0f);
    }
    __syncthreads();

    for (int i = tid; i < 5 * HD; i += 256) {
        const int o = i % HD, ll = i / HD;
        float acc = b4[o];
        #pragma unroll
        for (int k = 0; k < 5; ++k)
            #pragma unroll
            for (int ci = 0; ci < HD; ++ci)
                acc = fmaf(s3[ci * 13 + 2 * ll + k], sw4[(k * HD + ci) * HD + o], acc);
        h4out[(b * HD + o) * L4 + 5 * t + ll] = acc;
    }
}

// ---------------- Kernel 3: pool + linear + softmax + gumbel ----------------
__global__ __launch_bounds__(256) void k_tail(
    const float* __restrict__ h4,   // (NB, HD, L4)
    const float* __restrict__ wl, const float* __restrict__ bl,
    const float* __restrict__ unif,
    float* __restrict__ out_mw,   // (NB, CH, NM)
    float* __restrict__ out_ms)   // (NB, NS, CH, NM)
{
    const int b   = blockIdx.x;
    const int tid = threadIdx.x;
    __shared__ float red[HD * 25];
    __shared__ float hm[HD];
    __shared__ float lg[CH * NM];
    __shared__ float ltt[CH * NM];

    if (tid < HD * 25) {
        const int o = tid / 25, j = tid % 25;
        const float* p = h4 + (b * HD + o) * L4 + j * 5;
        red[tid] = p[0] + p[1] + p[2] + p[3] + p[4];
    }
    __syncthreads();
    if (tid < HD) {
        float s = 0.0f;
        #pragma unroll
        for (int j = 0; j < 25; ++j) s += red[tid * 25 + j];
        hm[tid] = s * (1.0f / (float)L4);
    }
    __syncthreads();
    if (tid < CH * NM) {
        float acc = bl[tid];
        #pragma unroll
        for (int k = 0; k < HD; ++k) acc = fmaf(wl[tid * HD + k], hm[k], acc);
        lg[tid] = acc;
    }
    __syncthreads();
    if (tid < CH) {
        float lv[NM];
        #pragma unroll
        for (int m = 0; m < NM; ++m) lv[m] = lg[tid * NM + m];
        const float m0 = fmaxf(fmaxf(lv[0], lv[1]), fmaxf(lv[2], lv[3]));
        float e[NM], s = 0.0f;
        #pragma unroll
        for (int m = 0; m < NM; ++m) {
            const float v = (lv[m] - m0) / 0.1f;
            ltt[tid * NM + m] = v;
            e[m] = __expf(v);
            s += e[m];
        }
        #pragma unroll
        for (int m = 0; m < NM; ++m)
            out_mw[(b * CH + tid) * NM + m] = e[m] / s;
    }
    __syncthreads();
    if (tid < NS * CH) {
        const int c = tid % CH, sI = tid / CH;
        const float* up = unif + ((b * NS + sI) * CH + c) * NM;
        float hh[NM], mx = -1e30f;
        #pragma unroll
        for (int m = 0; m < NM; ++m) {
            const float gu = -__logf(-__logf(up[m] + 1e-8f));
            hh[m] = (gu + ltt[c * NM + m]) / 0.1f;
            mx = fmaxf(mx, hh[m]);
        }
        float e2[NM], ss = 0.0f;
        #pragma unroll
        for (int m = 0; m < NM; ++m) { e2[m] = __expf(hh[m] - mx); ss += e2[m]; }
        #pragma unroll
        for (int m = 0; m < NM; ++m) {
            float y = e2[m] / ss;
            y = fminf(fmaxf(y, 1e-8f), 1.0f - 1e-8f);
            out_ms[((b * NS + sI) * CH + c) * NM + m] = y;
        }
    }
}

extern "C" void kernel_launch(void* const* d_in, const int* in_sizes, int n_in,
                              void* d_out, int out_size, void* d_ws, size_t ws_size,
                              hipStream_t stream) {
    const float* xc    = (const float*)d_in[0];
    const float* yc    = (const float*)d_in[1];
    const float* xg    = (const float*)d_in[2];
    const float* logls = (const float*)d_in[3];
    const float* w1    = (const float*)d_in[4];
    const float* b1    = (const float*)d_in[5];
    const float* w2    = (const float*)d_in[6];
    const float* b2    = (const float*)d_in[7];
    const float* w3    = (const float*)d_in[8];
    const float* b3    = (const float*)d_in[9];
    const float* w4    = (const float*)d_in[10];
    const float* b4    = (const float*)d_in[11];
    const float* wl    = (const float*)d_in[12];
    const float* bl    = (const float*)d_in[13];
    const float* unif  = (const float*)d_in[14];

    float* out = (float*)d_out;                 // reference outputs are float32
    float* out_den = out;                       // 131072
    float* out_rep = out + NB * G * CH;         // 131072
    float* out_mw  = out + 2 * NB * G * CH;     // 256
    float* out_ms  = out_mw + NB * CH * NM;     // 2560
    (void)out_size; (void)in_sizes; (void)n_in; (void)ws_size;

    float* ws_h4 = (float*)d_ws;                // NB*HD*L4 = 10000 f32 (40 KB)

    k_density<<<2048, 256, 0, stream>>>(xc, yc, xg, logls, out_den, out_rep);

    k_convnet<<<NB * 25, 256, 0, stream>>>(out_rep, w1, b1, w2, b2, w3, b3, w4, b4,
                                           ws_h4);

    k_tail<<<NB, 256, 0, stream>>>(ws_h4, wl, bl, unif, out_mw, out_ms);
}

// Round 18
// 26.168 us; speedup vs baseline: 1.3764x; 1.0612x over previous
//
#include <hip/hip_runtime.h>
#include <hip/hip_bf16.h>

// Problem constants (fixed by setup_inputs)
#define NB 8
#define G  2048
#define C  512
#define CH 8
#define NM 4
#define HD 10
#define NS 10
#define L1 1022
#define L2 509
#define L3 253
#define L4 125

typedef float v2f __attribute__((ext_vector_type(2)));

// ---------------- Kernel 1: RBF density + datarepr (packed-f32 inner loop) ------
// 2048 blocks x 256 threads (8 blocks/CU, 32 waves/CU). Block = (b,H, 64 g's);
// wave wv sums c-chunk [wv*128, wv*128+128). LDS SoA: sxx = s*xc, syy = yc,
// s = sqrt(-coef); arg = -(s*x - s*xx)^2. Inner loop per 2 c's:
// 2x ds_read_b64 (broadcast) + pk_sub + pk_mul + 2x v_exp + pk_add + pk_fma.
__global__ __launch_bounds__(256) void k_density(
    const float* __restrict__ xc, const float* __restrict__ yc,
    const float* __restrict__ xg, const float* __restrict__ logls,
    float* __restrict__ out_den,   // (nb,G,ch)
    float* __restrict__ out_rep)   // (nb,G,ch)
{
    __shared__ __align__(16) float sxx[C];   // 2 KB
    __shared__ __align__(16) float syy[C];   // 2 KB
    __shared__ float sden[4][64];
    __shared__ float snum[4][64];
    const int tid  = threadIdx.x;
    const int lane = tid & 63;
    const int wv   = tid >> 6;
    const int id = blockIdx.x;                 // 0..2047 = ((b*8+H)*32+gt)
    const int gt = id & 31;
    const int H  = (id >> 5) & 7;
    const int b  = id >> 8;

    // exp(-0.5 d^2/ls^2) == exp2( coef * d^2 ), coef = -0.5*log2(e)/ls^2 < 0
    const float coef = -0.72134752044448170f * __expf(-2.0f * logls[H]);
    const float s    = __builtin_amdgcn_sqrtf(-coef);

    for (int c = tid; c < C; c += 256) {
        sxx[c] = s * xc[(b * C + c) * CH + H];
        syy[c] = yc[(b * C + c) * CH + H];
    }
    __syncthreads();

    const int g = gt * 64 + lane;
    const float sx = s * xg[(b * G + g) * CH + H];
    const v2f sx2 = {sx, sx};

    const float* px = sxx + wv * 128;
    const float* py = syy + wv * 128;

    v2f den2 = {0.0f, 0.0f}, num2 = {0.0f, 0.0f};
    #pragma unroll 8
    for (int c2 = 0; c2 < 64; ++c2) {
        const v2f xv = *(const v2f*)(px + 2 * c2);   // ds_read_b64, broadcast
        const v2f yv = *(const v2f*)(py + 2 * c2);   // ds_read_b64, broadcast
        const v2f d = sx2 - xv;                      // v_pk_add (neg)
        const v2f m = d * d;                         // v_pk_mul
        v2f w;
        w.x = __builtin_amdgcn_exp2f(-m.x);          // v_exp_f32 (neg mod)
        w.y = __builtin_amdgcn_exp2f(-m.y);          // v_exp_f32 (neg mod)
        den2 += w;                                   // v_pk_add
        num2 = __builtin_elementwise_fma(w, yv, num2); // v_pk_fma
    }
    const float den = den2.x + den2.y;
    const float num = num2.x + num2.y;

    sden[wv][lane] = den;
    snum[wv][lane] = num;
    __syncthreads();

    if (tid < 64) {
        const float dtot = sden[0][tid] + sden[1][tid] + sden[2][tid] + sden[3][tid];
        const float ntot = snum[0][tid] + snum[1][tid] + snum[2][tid] + snum[3][tid];
        const int o = (b * G + gt * 64 + tid) * CH + H;
        out_den[o] = dtot;
        out_rep[o] = ntot / (dtot + 1e-4f);
    }
}

// ---------------- Kernel 2: full conv1..4 stencil chain, tiled with halo -------
__global__ __launch_bounds__(256) void k_convnet(
    const float* __restrict__ rep,
    const float* __restrict__ w1, const float* __restrict__ b1,
    const float* __restrict__ w2, const float* __restrict__ b2,
    const float* __restrict__ w3, const float* __restrict__ b3,
    const float* __restrict__ w4, const float* __restrict__ b4,
    float* __restrict__ h4out)   // (NB, HD, L4)
{
    const int b   = blockIdx.x / 25;
    const int t   = blockIdx.x % 25;
    const int tid = threadIdx.x;

    __shared__ float sxt[CH * 125];      // rep tile, [ci][125]
    __shared__ float sw1[5 * CH * HD];   // [k][ci][o]
    __shared__ float sw2[5 * HD * HD];
    __shared__ float sw3[5 * HD * HD];
    __shared__ float sw4[5 * HD * HD];
    __shared__ float s1[HD * 61];        // [ci][61]
    __shared__ float s2[HD * 29];
    __shared__ float s3[HD * 13];

    {
        const float* src = rep + (b * G + 80 * t) * CH;
        for (int i = tid; i < 125 * CH; i += 256) {
            const int gl = i >> 3, ci = i & 7;
            sxt[ci * 125 + gl] = src[i];
        }
    }
    for (int i = tid; i < HD * CH * 5; i += 256) {
        const int o = i / 40, ci = (i / 5) % 8, k = i % 5;
        sw1[(k * CH + ci) * HD + o] = w1[i];
    }
    for (int i = tid; i < HD * HD * 5; i += 256) {
        const int o = i / 50, ci = (i / 5) % 10, k = i % 5;
        sw2[(k * HD + ci) * HD + o] = w2[i];
        sw3[(k * HD + ci) * HD + o] = w3[i];
        sw4[(k * HD + ci) * HD + o] = w4[i];
    }
    __syncthreads();

    for (int i = tid; i < 61 * HD; i += 256) {
        const int o = i % HD, ll = i / HD;
        float acc = b1[o];
        #pragma unroll
        for (int k = 0; k < 5; ++k)
            #pragma unroll
            for (int ci = 0; ci < CH; ++ci)
                acc = fmaf(sxt[ci * 125 + 2 * ll + k], sw1[(k * CH + ci) * HD + o], acc);
        s1[o * 61 + ll] = fmaxf(acc, 0.0f);
    }
    __syncthreads();

    for (int i = tid; i < 29 * HD; i += 256) {
        const int o = i % HD, ll = i / HD;
        float acc = b2[o];
        #pragma unroll
        for (int k = 0; k < 5; ++k)
            #pragma unroll
            for (int ci = 0; ci < HD; ++ci)
                acc = fmaf(s1[ci * 61 + 2 * ll + k], sw2[(k * HD + ci) * HD + o], acc);
        s2[o * 29 + ll] = fmaxf(acc, 0.0f);
    }
    __syncthreads();

    for (int i = tid; i < 13 * HD; i += 256) {
        const int o = i % HD, ll = i / HD;
        float acc = b3[o];
        #pragma unroll
        for (int k = 0; k < 5; ++k)
            #pragma unroll
            for (int ci = 0; ci < HD; ++ci)
                acc = fmaf(s2[ci * 29 + 2 * ll + k], sw3[(k * HD + ci) * HD + o], acc);
        s3[o * 13 + ll] = fmaxf(acc, 0.0f);
    }
    __syncthreads();

    for (int i = tid; i < 5 * HD; i += 256) {
        const int o = i % HD, ll = i / HD;
        float acc = b4[o];
        #pragma unroll
        for (int k = 0; k < 5; ++k)
            #pragma unroll
            for (int ci = 0; ci < HD; ++ci)
                acc = fmaf(s3[ci * 13 + 2 * ll + k], sw4[(k * HD + ci) * HD + o], acc);
        h4out[(b * HD + o) * L4 + 5 * t + ll] = acc;
    }
}

// ---------------- Kernel 3: pool + linear + softmax + gumbel ----------------
__global__ __launch_bounds__(256) void k_tail(
    const float* __restrict__ h4,   // (NB, HD, L4)
    const float* __restrict__ wl, const float* __restrict__ bl,
    const float* __restrict__ unif,
    float* __restrict__ out_mw,   // (NB, CH, NM)
    float* __restrict__ out_ms)   // (NB, NS, CH, NM)
{
    const int b   = blockIdx.x;
    const int tid = threadIdx.x;
    __shared__ float red[HD * 25];
    __shared__ float hm[HD];
    __shared__ float lg[CH * NM];
    __shared__ float ltt[CH * NM];

    if (tid < HD * 25) {
        const int o = tid / 25, j = tid % 25;
        const float* p = h4 + (b * HD + o) * L4 + j * 5;
        red[tid] = p[0] + p[1] + p[2] + p[3] + p[4];
    }
    __syncthreads();
    if (tid < HD) {
        float s = 0.0f;
        #pragma unroll
        for (int j = 0; j < 25; ++j) s += red[tid * 25 + j];
        hm[tid] = s * (1.0f / (float)L4);
    }
    __syncthreads();
    if (tid < CH * NM) {
        float acc = bl[tid];
        #pragma unroll
        for (int k = 0; k < HD; ++k) acc = fmaf(wl[tid * HD + k], hm[k], acc);
        lg[tid] = acc;
    }
    __syncthreads();
    if (tid < CH) {
        float lv[NM];
        #pragma unroll
        for (int m = 0; m < NM; ++m) lv[m] = lg[tid * NM + m];
        const float m0 = fmaxf(fmaxf(lv[0], lv[1]), fmaxf(lv[2], lv[3]));
        float e[NM], s = 0.0f;
        #pragma unroll
        for (int m = 0; m < NM; ++m) {
            const float v = (lv[m] - m0) / 0.1f;
            ltt[tid * NM + m] = v;
            e[m] = __expf(v);
            s += e[m];
        }
        #pragma unroll
        for (int m = 0; m < NM; ++m)
            out_mw[(b * CH + tid) * NM + m] = e[m] / s;
    }
    __syncthreads();
    if (tid < NS * CH) {
        const int c = tid % CH, sI = tid / CH;
        const float* up = unif + ((b * NS + sI) * CH + c) * NM;
        float hh[NM], mx = -1e30f;
        #pragma unroll
        for (int m = 0; m < NM; ++m) {
            const float gu = -__logf(-__logf(up[m] + 1e-8f));
            hh[m] = (gu + ltt[c * NM + m]) / 0.1f;
            mx = fmaxf(mx, hh[m]);
        }
        float e2[NM], ss = 0.0f;
        #pragma unroll
        for (int m = 0; m < NM; ++m) { e2[m] = __expf(hh[m] - mx); ss += e2[m]; }
        #pragma unroll
        for (int m = 0; m < NM; ++m) {
            float y = e2[m] / ss;
            y = fminf(fmaxf(y, 1e-8f), 1.0f - 1e-8f);
            out_ms[((b * NS + sI) * CH + c) * NM + m] = y;
        }
    }
}

extern "C" void kernel_launch(void* const* d_in, const int* in_sizes, int n_in,
                              void* d_out, int out_size, void* d_ws, size_t ws_size,
                              hipStream_t stream) {
    const float* xc    = (const float*)d_in[0];
    const float* yc    = (const float*)d_in[1];
    const float* xg    = (const float*)d_in[2];
    const float* logls = (const float*)d_in[3];
    const float* w1    = (const float*)d_in[4];
    const float* b1    = (const float*)d_in[5];
    const float* w2    = (const float*)d_in[6];
    const float* b2    = (const float*)d_in[7];
    const float* w3    = (const float*)d_in[8];
    const float* b3    = (const float*)d_in[9];
    const float* w4    = (const float*)d_in[10];
    const float* b4    = (const float*)d_in[11];
    const float* wl    = (const float*)d_in[12];
    const float* bl    = (const float*)d_in[13];
    const float* unif  = (const float*)d_in[14];

    float* out = (float*)d_out;                 // reference outputs are float32
    float* out_den = out;                       // 131072
    float* out_rep = out + NB * G * CH;         // 131072
    float* out_mw  = out + 2 * NB * G * CH;     // 256
    float* out_ms  = out_mw + NB * CH * NM;     // 2560
    (void)out_size; (void)in_sizes; (void)n_in; (void)ws_size;

    float* ws_h4 = (float*)d_ws;                // NB*HD*L4 = 10000 f32 (40 KB)

    k_density<<<2048, 256, 0, stream>>>(xc, yc, xg, logls, out_den, out_rep);

    k_convnet<<<NB * 25, 256, 0, stream>>>(out_rep, w1, b1, w2, b2, w3, b3, w4, b4,
                                           ws_h4);

    k_tail<<<NB, 256, 0, stream>>>(ws_h4, wl, bl, unif, out_mw, out_ms);
}